// Round 6
// baseline (1871.484 us; speedup 1.0000x reference)
//
#include <hip/hip_runtime.h>
#include <hip/hip_bf16.h>

#define HDIM 128
#define G3 384          // 3*H
#define EDIM 300
#define BATCH 64
#define LSTO 1024
#define QLEN 32
#define NSENT 16

typedef float4 f4;

__device__ __forceinline__ float sigmf(float x) { return 1.0f / (1.0f + __expf(-x)); }
__device__ __forceinline__ float tanhfast(float x) {
    float e = __expf(-2.0f * x);
    return (1.0f - e) / (1.0f + e);
}

// ---------------------------------------------------------------------------
// K1: gi[row][g] = b_ih[g] + emb[tok[row]] . w_ih[g]   (K = 300), bf16 out
// 32 rows per WG staged in LDS; 192 threads, each handles g and g+192.
// ---------------------------------------------------------------------------
__global__ __launch_bounds__(192) void k_gi_gather(
    const int* __restrict__ toks, int nrows,
    const float* __restrict__ emb,
    const float* __restrict__ w_ih, const float* __restrict__ b_ih,
    __hip_bfloat16* __restrict__ gi)
{
    __shared__ alignas(16) float a_lds[32 * EDIM];
    int tid = threadIdx.x;
    int rowbase = blockIdx.x * 32;

    for (int i = tid; i < 32 * 75; i += 192) {   // 75 = 300/4
        int r = i / 75, e4 = i - r * 75;
        int row = rowbase + r;
        int tok = (row < nrows) ? toks[row] : 0;
        f4 v = *reinterpret_cast<const f4*>(emb + (size_t)tok * EDIM + e4 * 4);
        *reinterpret_cast<f4*>(a_lds + r * EDIM + e4 * 4) = v;
    }
    __syncthreads();

    int g0 = tid, g1 = tid + 192;
    float acc0[32], acc1[32];
#pragma unroll
    for (int r = 0; r < 32; r++) { acc0[r] = 0.f; acc1[r] = 0.f; }

    const float* w0p = w_ih + (size_t)g0 * EDIM;
    const float* w1p = w_ih + (size_t)g1 * EDIM;
    for (int e4 = 0; e4 < 75; ++e4) {
        f4 w0 = *reinterpret_cast<const f4*>(w0p + e4 * 4);
        f4 w1 = *reinterpret_cast<const f4*>(w1p + e4 * 4);
#pragma unroll
        for (int r = 0; r < 32; r++) {
            f4 a = *reinterpret_cast<const f4*>(a_lds + r * EDIM + e4 * 4);
            acc0[r] += a.x * w0.x + a.y * w0.y + a.z * w0.z + a.w * w0.w;
            acc1[r] += a.x * w1.x + a.y * w1.y + a.z * w1.z + a.w * w1.w;
        }
    }
    float bb0 = b_ih[g0], bb1 = b_ih[g1];
    for (int r = 0; r < 32; r++) {
        int row = rowbase + r;
        if (row < nrows) {
            gi[(size_t)row * G3 + g0] = __float2bfloat16(acc0[r] + bb0);
            gi[(size_t)row * G3 + g1] = __float2bfloat16(acc1[r] + bb1);
        }
    }
}

// ---------------------------------------------------------------------------
// K1b: dense variant, K = 128 (episodic gi from sents)
// ---------------------------------------------------------------------------
__global__ __launch_bounds__(192) void k_gi_dense(
    const float* __restrict__ x, int nrows,
    const float* __restrict__ w_ih, const float* __restrict__ b_ih,
    __hip_bfloat16* __restrict__ gi)
{
    __shared__ alignas(16) float a_lds[32 * HDIM];
    int tid = threadIdx.x;
    int rowbase = blockIdx.x * 32;

    for (int i = tid; i < 32 * 32; i += 192) {   // 32 = 128/4
        int r = i >> 5, e4 = i & 31;
        int row = rowbase + r;
        f4 v;
        if (row < nrows) v = *reinterpret_cast<const f4*>(x + (size_t)row * HDIM + e4 * 4);
        else { v.x = v.y = v.z = v.w = 0.f; }
        *reinterpret_cast<f4*>(a_lds + r * HDIM + e4 * 4) = v;
    }
    __syncthreads();

    int g0 = tid, g1 = tid + 192;
    float acc0[32], acc1[32];
#pragma unroll
    for (int r = 0; r < 32; r++) { acc0[r] = 0.f; acc1[r] = 0.f; }

    const float* w0p = w_ih + (size_t)g0 * HDIM;
    const float* w1p = w_ih + (size_t)g1 * HDIM;
    for (int e4 = 0; e4 < 32; ++e4) {
        f4 w0 = *reinterpret_cast<const f4*>(w0p + e4 * 4);
        f4 w1 = *reinterpret_cast<const f4*>(w1p + e4 * 4);
#pragma unroll
        for (int r = 0; r < 32; r++) {
            f4 a = *reinterpret_cast<const f4*>(a_lds + r * HDIM + e4 * 4);
            acc0[r] += a.x * w0.x + a.y * w0.y + a.z * w0.z + a.w * w0.w;
            acc1[r] += a.x * w1.x + a.y * w1.y + a.z * w1.z + a.w * w1.w;
        }
    }
    float bb0 = b_ih[g0], bb1 = b_ih[g1];
    for (int r = 0; r < 32; r++) {
        int row = rowbase + r;
        if (row < nrows) {
            gi[(size_t)row * G3 + g0] = __float2bfloat16(acc0[r] + bb0);
            gi[(size_t)row * G3 + g1] = __float2bfloat16(acc1[r] + bb1);
        }
    }
}

// ---------------------------------------------------------------------------
// K2: sequential GRU scan, one workgroup per batch element.
// 384 threads (6 waves); thread g holds w_hh row g in 32 NAMED f4 registers
// (128 VGPRs, not an indexable array -> cannot be demoted to scratch).
// Per step: prefetch gi -> dot(h, w) -> gh_lds -> barrier -> elementwise
// update by threads 0..127 -> barrier.
// ---------------------------------------------------------------------------
#define WDECL(I) const f4 w##I = wp[I];
#define DOT(I, ACC) { f4 h_##I = hp[I];                                   \
    ACC += h_##I.x * w##I.x + h_##I.y * w##I.y +                          \
           h_##I.z * w##I.z + h_##I.w * w##I.w; }

template <int MODE>
__global__ __launch_bounds__(384, 1) void k_scan(
    const __hip_bfloat16* __restrict__ gi,   // [BATCH*T][384]
    int T,
    const float* __restrict__ w_hh, const float* __restrict__ b_hh,
    const int* __restrict__ mask,            // MODE 0
    float* __restrict__ sents,               // MODE 0
    const int* __restrict__ qtoks,           // MODE 1
    float* __restrict__ qv_out,              // MODE 1 (d_out)
    float* __restrict__ q_ws,                // MODE 1
    const float* __restrict__ gates,         // MODE 2
    float* __restrict__ h_out,               // MODE 2 (mem ws)
    float* __restrict__ ep_out)              // MODE 2 (d_out, nullable)
{
    __shared__ alignas(16) float h_lds[HDIM];
    __shared__ float gh_lds[G3];

    int tid = threadIdx.x;          // 0..383, = output gate index g
    int b = blockIdx.x;

    const f4* wp = reinterpret_cast<const f4*>(w_hh + (size_t)tid * HDIM);
    WDECL(0)  WDECL(1)  WDECL(2)  WDECL(3)  WDECL(4)  WDECL(5)  WDECL(6)  WDECL(7)
    WDECL(8)  WDECL(9)  WDECL(10) WDECL(11) WDECL(12) WDECL(13) WDECL(14) WDECL(15)
    WDECL(16) WDECL(17) WDECL(18) WDECL(19) WDECL(20) WDECL(21) WDECL(22) WDECL(23)
    WDECL(24) WDECL(25) WDECL(26) WDECL(27) WDECL(28) WDECL(29) WDECL(30) WDECL(31)
    float bb = b_hh[tid];

    if (tid < HDIM) h_lds[tid] = 0.f;

    int qi = QLEN - 1;
    if (MODE == 1) {
        for (int t2 = QLEN - 2; t2 >= 0; --t2)
            if (qtoks[b * QLEN + t2 + 1] == 0) qi = t2;
    }
    int scnt = 0;
    __syncthreads();

    const __hip_bfloat16* gib = gi + (size_t)b * T * G3;
    const f4* hp = reinterpret_cast<const f4*>(h_lds);

    for (int t = 0; t < T; ++t) {
        // ---- phase 0: issue this step's gi (+mask/gate) loads, raw regs ----
        __hip_bfloat16 gr_r, gr_z, gr_n;
        int m = 0;
        float wgate = 0.f;
        if (tid < HDIM) {
            const __hip_bfloat16* gr = gib + (size_t)t * G3;
            gr_r = gr[tid];
            gr_z = gr[HDIM + tid];
            gr_n = gr[2 * HDIM + tid];
            if (MODE == 0) m = mask[b * LSTO + t];
            if (MODE == 2) wgate = gates[b * NSENT + t];
        }

        // ---- phase 1: gh[g] = bb + h . w  (4 independent accumulators) ----
        float a0 = bb, a1 = 0.f, a2 = 0.f, a3 = 0.f;
        DOT(0, a0)  DOT(1, a1)  DOT(2, a2)  DOT(3, a3)
        DOT(4, a0)  DOT(5, a1)  DOT(6, a2)  DOT(7, a3)
        DOT(8, a0)  DOT(9, a1)  DOT(10, a2) DOT(11, a3)
        DOT(12, a0) DOT(13, a1) DOT(14, a2) DOT(15, a3)
        DOT(16, a0) DOT(17, a1) DOT(18, a2) DOT(19, a3)
        DOT(20, a0) DOT(21, a1) DOT(22, a2) DOT(23, a3)
        DOT(24, a0) DOT(25, a1) DOT(26, a2) DOT(27, a3)
        DOT(28, a0) DOT(29, a1) DOT(30, a2) DOT(31, a3)
        gh_lds[tid] = (a0 + a1) + (a2 + a3);
        __syncthreads();

        // ---- phase 2: elementwise GRU cell on threads 0..127 ----
        if (tid < HDIM) {
            int j = tid;
            float r = sigmf(__bfloat162float(gr_r) + gh_lds[j]);
            float z = sigmf(__bfloat162float(gr_z) + gh_lds[HDIM + j]);
            float n = tanhfast(__bfloat162float(gr_n) + r * gh_lds[2 * HDIM + j]);
            float hprev = h_lds[j];
            float hn = (1.f - z) * n + z * hprev;
            if (MODE == 2) {
                hn = wgate * hn + (1.f - wgate) * hprev;
            }
            h_lds[j] = hn;

            if (MODE == 0) {
                if (m) {
                    if (scnt < NSENT)
                        sents[((size_t)b * NSENT + scnt) * HDIM + j] = hn;
                    scnt++;
                }
            }
            if (MODE == 1 && t == qi) {
                qv_out[b * HDIM + j] = hn;
                q_ws[b * HDIM + j] = hn;
            }
            if (MODE == 2 && t == T - 1) {
                h_out[b * HDIM + j] = hn;
                if (ep_out) ep_out[b * HDIM + j] = hn;
            }
        }
        __syncthreads();
    }
}

// ---------------------------------------------------------------------------
// K3: attention gates.  WG per batch, 128 threads = (16 t) x (8 segments).
// ---------------------------------------------------------------------------
__global__ __launch_bounds__(128) void k_gates(
    const float* __restrict__ sents, const float* __restrict__ q_ws,
    const float* __restrict__ mem, const float* __restrict__ gate_w,
    const float* __restrict__ gate_b,
    float* __restrict__ gates_ws, float* __restrict__ gout)
{
    int b = blockIdx.x, tid = threadIdx.x;
    int t = tid >> 3, s = tid & 7;
    float p = 0.f;
    const float* sv = sents + ((size_t)b * NSENT + t) * HDIM;
    for (int jj = 0; jj < 16; jj++) {
        int j = s * 16 + jj;
        float S = sv[j], Q = q_ws[b * HDIM + j], M = mem[b * HDIM + j];
        float dq = S - Q, dm = S - M;
        p += (S * Q) * gate_w[j] + (S * M) * gate_w[HDIM + j] +
             (dq * dq) * gate_w[2 * HDIM + j] + (dm * dm) * gate_w[3 * HDIM + j];
    }
    __shared__ float red[16][8];
    red[t][s] = p;
    __syncthreads();
    if (s == 0) {
        float sum = 0.f;
        for (int k = 0; k < 8; k++) sum += red[t][k];
        float gt = sigmf(sum + gate_b[0]);
        gates_ws[b * NSENT + t] = gt;
        if (gout) gout[b * NSENT + t] = gt;
    }
}

// ---------------------------------------------------------------------------
extern "C" void kernel_launch(void* const* d_in, const int* in_sizes, int n_in,
                              void* d_out, int out_size, void* d_ws, size_t ws_size,
                              hipStream_t stream)
{
    const int*   x_sto    = (const int*)d_in[0];
    const int*   x_mask   = (const int*)d_in[1];
    const int*   x_q      = (const int*)d_in[2];
    const float* emb      = (const float*)d_in[4];
    const float* enc_w_ih = (const float*)d_in[5];
    const float* enc_w_hh = (const float*)d_in[6];
    const float* enc_b_ih = (const float*)d_in[7];
    const float* enc_b_hh = (const float*)d_in[8];
    const float* gate_w   = (const float*)d_in[9];
    const float* gate_b   = (const float*)d_in[10];
    const float* ep_w_ih  = (const float*)d_in[11];
    const float* ep_w_hh  = (const float*)d_in[12];
    const float* ep_b_ih  = (const float*)d_in[13];
    const float* ep_b_hh  = (const float*)d_in[14];

    float* out_q  = (float*)d_out;                       // (64,128)
    float* out_ep = (float*)d_out + BATCH * HDIM;        // (1,64,128)
    float* out_g  = (float*)d_out + 2 * BATCH * HDIM;    // (64,16)

    char* ws = (char*)d_ws;
    size_t off = 0;
    auto alloc = [&](size_t bytes) {
        void* p = ws + off;
        off += (bytes + 255) & ~(size_t)255;
        return p;
    };
    __hip_bfloat16* gi_sto = (__hip_bfloat16*)alloc((size_t)BATCH * LSTO * G3 * 2);
    __hip_bfloat16* gi_q   = (__hip_bfloat16*)alloc((size_t)BATCH * QLEN * G3 * 2);
    __hip_bfloat16* gi_ep  = (__hip_bfloat16*)alloc((size_t)BATCH * NSENT * G3 * 2);
    float* sents    = (float*)alloc((size_t)BATCH * NSENT * HDIM * 4);
    float* q_ws     = (float*)alloc((size_t)BATCH * HDIM * 4);
    float* mem      = (float*)alloc((size_t)BATCH * HDIM * 4);
    float* gates_ws = (float*)alloc((size_t)BATCH * NSENT * 4);
    (void)ws_size; (void)in_sizes; (void)n_in; (void)out_size;

    // Phase A: input-projection GEMMs (gather + matmul), bf16 output
    k_gi_gather<<<(BATCH * LSTO) / 32, 192, 0, stream>>>(
        x_sto, BATCH * LSTO, emb, enc_w_ih, enc_b_ih, gi_sto);
    k_gi_gather<<<(BATCH * QLEN) / 32, 192, 0, stream>>>(
        x_q, BATCH * QLEN, emb, enc_w_ih, enc_b_ih, gi_q);

    // Phase B: story scan (writes sents), question scan (writes q_vecs)
    k_scan<0><<<BATCH, 384, 0, stream>>>(
        gi_sto, LSTO, enc_w_hh, enc_b_hh,
        x_mask, sents, nullptr, nullptr, nullptr, nullptr, nullptr, nullptr);
    k_scan<1><<<BATCH, 384, 0, stream>>>(
        gi_q, QLEN, enc_w_hh, enc_b_hh,
        nullptr, nullptr, x_q, out_q, q_ws, nullptr, nullptr, nullptr);

    // Phase C: episodic memory, 3 iterations
    k_gi_dense<<<(BATCH * NSENT) / 32, 192, 0, stream>>>(
        sents, BATCH * NSENT, ep_w_ih, ep_b_ih, gi_ep);

    for (int it = 0; it < 3; ++it) {
        const float* msrc = (it == 0) ? q_ws : mem;
        k_gates<<<BATCH, 128, 0, stream>>>(
            sents, q_ws, msrc, gate_w, gate_b, gates_ws,
            (it == 2) ? out_g : nullptr);
        k_scan<2><<<BATCH, 384, 0, stream>>>(
            gi_ep, NSENT, ep_w_hh, ep_b_hh,
            nullptr, nullptr, nullptr, nullptr, nullptr,
            gates_ws, mem, (it == 2) ? out_ep : nullptr);
    }
}

// Round 7
// 1731.814 us; speedup vs baseline: 1.0806x; 1.0806x over previous
//
#include <hip/hip_runtime.h>
#include <hip/hip_bf16.h>

#define HDIM 128
#define G3 384          // 3*H
#define EDIM 300
#define BATCH 64
#define LSTO 1024
#define QLEN 32
#define NSENT 16

typedef float4 f4;
typedef float fv4 __attribute__((ext_vector_type(4)));

__device__ __forceinline__ float sigmf(float x) { return 1.0f / (1.0f + __expf(-x)); }
__device__ __forceinline__ float tanhfast(float x) {
    float e = __expf(-2.0f * x);
    return (1.0f - e) / (1.0f + e);
}

// ---------------------------------------------------------------------------
// K1: gi[row][g] = b_ih[g] + emb[tok[row]] . w_ih[g]   (K = 300), bf16 out
// ---------------------------------------------------------------------------
__global__ __launch_bounds__(192) void k_gi_gather(
    const int* __restrict__ toks, int nrows,
    const float* __restrict__ emb,
    const float* __restrict__ w_ih, const float* __restrict__ b_ih,
    __hip_bfloat16* __restrict__ gi)
{
    __shared__ alignas(16) float a_lds[32 * EDIM];
    int tid = threadIdx.x;
    int rowbase = blockIdx.x * 32;

    for (int i = tid; i < 32 * 75; i += 192) {   // 75 = 300/4
        int r = i / 75, e4 = i - r * 75;
        int row = rowbase + r;
        int tok = (row < nrows) ? toks[row] : 0;
        f4 v = *reinterpret_cast<const f4*>(emb + (size_t)tok * EDIM + e4 * 4);
        *reinterpret_cast<f4*>(a_lds + r * EDIM + e4 * 4) = v;
    }
    __syncthreads();

    int g0 = tid, g1 = tid + 192;
    float acc0[32], acc1[32];
#pragma unroll
    for (int r = 0; r < 32; r++) { acc0[r] = 0.f; acc1[r] = 0.f; }

    const float* w0p = w_ih + (size_t)g0 * EDIM;
    const float* w1p = w_ih + (size_t)g1 * EDIM;
    for (int e4 = 0; e4 < 75; ++e4) {
        f4 w0 = *reinterpret_cast<const f4*>(w0p + e4 * 4);
        f4 w1 = *reinterpret_cast<const f4*>(w1p + e4 * 4);
#pragma unroll
        for (int r = 0; r < 32; r++) {
            f4 a = *reinterpret_cast<const f4*>(a_lds + r * EDIM + e4 * 4);
            acc0[r] += a.x * w0.x + a.y * w0.y + a.z * w0.z + a.w * w0.w;
            acc1[r] += a.x * w1.x + a.y * w1.y + a.z * w1.z + a.w * w1.w;
        }
    }
    float bb0 = b_ih[g0], bb1 = b_ih[g1];
    for (int r = 0; r < 32; r++) {
        int row = rowbase + r;
        if (row < nrows) {
            gi[(size_t)row * G3 + g0] = __float2bfloat16(acc0[r] + bb0);
            gi[(size_t)row * G3 + g1] = __float2bfloat16(acc1[r] + bb1);
        }
    }
}

// ---------------------------------------------------------------------------
// K1b: dense variant, K = 128 (episodic gi from sents)
// ---------------------------------------------------------------------------
__global__ __launch_bounds__(192) void k_gi_dense(
    const float* __restrict__ x, int nrows,
    const float* __restrict__ w_ih, const float* __restrict__ b_ih,
    __hip_bfloat16* __restrict__ gi)
{
    __shared__ alignas(16) float a_lds[32 * HDIM];
    int tid = threadIdx.x;
    int rowbase = blockIdx.x * 32;

    for (int i = tid; i < 32 * 32; i += 192) {   // 32 = 128/4
        int r = i >> 5, e4 = i & 31;
        int row = rowbase + r;
        f4 v;
        if (row < nrows) v = *reinterpret_cast<const f4*>(x + (size_t)row * HDIM + e4 * 4);
        else { v.x = v.y = v.z = v.w = 0.f; }
        *reinterpret_cast<f4*>(a_lds + r * HDIM + e4 * 4) = v;
    }
    __syncthreads();

    int g0 = tid, g1 = tid + 192;
    float acc0[32], acc1[32];
#pragma unroll
    for (int r = 0; r < 32; r++) { acc0[r] = 0.f; acc1[r] = 0.f; }

    const float* w0p = w_ih + (size_t)g0 * HDIM;
    const float* w1p = w_ih + (size_t)g1 * HDIM;
    for (int e4 = 0; e4 < 32; ++e4) {
        f4 w0 = *reinterpret_cast<const f4*>(w0p + e4 * 4);
        f4 w1 = *reinterpret_cast<const f4*>(w1p + e4 * 4);
#pragma unroll
        for (int r = 0; r < 32; r++) {
            f4 a = *reinterpret_cast<const f4*>(a_lds + r * HDIM + e4 * 4);
            acc0[r] += a.x * w0.x + a.y * w0.y + a.z * w0.z + a.w * w0.w;
            acc1[r] += a.x * w1.x + a.y * w1.y + a.z * w1.z + a.w * w1.w;
        }
    }
    float bb0 = b_ih[g0], bb1 = b_ih[g1];
    for (int r = 0; r < 32; r++) {
        int row = rowbase + r;
        if (row < nrows) {
            gi[(size_t)row * G3 + g0] = __float2bfloat16(acc0[r] + bb0);
            gi[(size_t)row * G3 + g1] = __float2bfloat16(acc1[r] + bb1);
        }
    }
}

// ---------------------------------------------------------------------------
// K2: sequential GRU scan, one workgroup per batch element.
// 384 threads (6 waves); thread g holds w_hh row g in 32 f4 registers,
// PINNED via asm so the scheduler cannot rematerialize the loads in-loop.
// ---------------------------------------------------------------------------
#define WDECL(I) fv4 w##I = wp[I]; asm volatile("" : "+v"(w##I));
#define DOT(I, ACC) { fv4 h_##I = hp[I];                                  \
    ACC += h_##I.x * w##I.x + h_##I.y * w##I.y +                          \
           h_##I.z * w##I.z + h_##I.w * w##I.w; }

template <int MODE>
__global__ __launch_bounds__(384, 1) void k_scan(
    const __hip_bfloat16* __restrict__ gi,   // [BATCH*T][384]
    int T,
    const float* __restrict__ w_hh, const float* __restrict__ b_hh,
    const int* __restrict__ mask,            // MODE 0
    float* __restrict__ sents,               // MODE 0
    const int* __restrict__ qtoks,           // MODE 1
    float* __restrict__ qv_out,              // MODE 1 (d_out)
    float* __restrict__ q_ws,                // MODE 1
    const float* __restrict__ gates,         // MODE 2
    float* __restrict__ h_out,               // MODE 2 (mem ws)
    float* __restrict__ ep_out)              // MODE 2 (d_out, nullable)
{
    __shared__ alignas(16) float h_lds[HDIM];
    __shared__ float gh_lds[G3];

    int tid = threadIdx.x;          // 0..383, = output gate index g
    int b = blockIdx.x;

    const fv4* wp = reinterpret_cast<const fv4*>(w_hh + (size_t)tid * HDIM);
    WDECL(0)  WDECL(1)  WDECL(2)  WDECL(3)  WDECL(4)  WDECL(5)  WDECL(6)  WDECL(7)
    WDECL(8)  WDECL(9)  WDECL(10) WDECL(11) WDECL(12) WDECL(13) WDECL(14) WDECL(15)
    WDECL(16) WDECL(17) WDECL(18) WDECL(19) WDECL(20) WDECL(21) WDECL(22) WDECL(23)
    WDECL(24) WDECL(25) WDECL(26) WDECL(27) WDECL(28) WDECL(29) WDECL(30) WDECL(31)
    float bb = b_hh[tid];

    if (tid < HDIM) h_lds[tid] = 0.f;

    int qi = QLEN - 1;
    if (MODE == 1) {
        for (int t2 = QLEN - 2; t2 >= 0; --t2)
            if (qtoks[b * QLEN + t2 + 1] == 0) qi = t2;
    }
    int scnt = 0;
    __syncthreads();

    const __hip_bfloat16* gib = gi + (size_t)b * T * G3;
    const fv4* hp = reinterpret_cast<const fv4*>(h_lds);

    for (int t = 0; t < T; ++t) {
        // ---- phase 0: issue this step's gi (+mask/gate) loads, raw regs ----
        __hip_bfloat16 gr_r, gr_z, gr_n;
        int m = 0;
        float wgate = 0.f;
        if (tid < HDIM) {
            const __hip_bfloat16* gr = gib + (size_t)t * G3;
            gr_r = gr[tid];
            gr_z = gr[HDIM + tid];
            gr_n = gr[2 * HDIM + tid];
            if (MODE == 0) m = mask[b * LSTO + t];
            if (MODE == 2) wgate = gates[b * NSENT + t];
        }

        // ---- phase 1: gh[g] = bb + h . w  (4 independent accumulators) ----
        float a0 = bb, a1 = 0.f, a2 = 0.f, a3 = 0.f;
        DOT(0, a0)  DOT(1, a1)  DOT(2, a2)  DOT(3, a3)
        DOT(4, a0)  DOT(5, a1)  DOT(6, a2)  DOT(7, a3)
        DOT(8, a0)  DOT(9, a1)  DOT(10, a2) DOT(11, a3)
        DOT(12, a0) DOT(13, a1) DOT(14, a2) DOT(15, a3)
        DOT(16, a0) DOT(17, a1) DOT(18, a2) DOT(19, a3)
        DOT(20, a0) DOT(21, a1) DOT(22, a2) DOT(23, a3)
        DOT(24, a0) DOT(25, a1) DOT(26, a2) DOT(27, a3)
        DOT(28, a0) DOT(29, a1) DOT(30, a2) DOT(31, a3)
        gh_lds[tid] = (a0 + a1) + (a2 + a3);
        __syncthreads();

        // ---- phase 2: elementwise GRU cell on threads 0..127 ----
        if (tid < HDIM) {
            int j = tid;
            float r = sigmf(__bfloat162float(gr_r) + gh_lds[j]);
            float z = sigmf(__bfloat162float(gr_z) + gh_lds[HDIM + j]);
            float n = tanhfast(__bfloat162float(gr_n) + r * gh_lds[2 * HDIM + j]);
            float hprev = h_lds[j];
            float hn = (1.f - z) * n + z * hprev;
            if (MODE == 2) {
                hn = wgate * hn + (1.f - wgate) * hprev;
            }
            h_lds[j] = hn;

            if (MODE == 0) {
                if (m) {
                    if (scnt < NSENT)
                        sents[((size_t)b * NSENT + scnt) * HDIM + j] = hn;
                    scnt++;
                }
            }
            if (MODE == 1 && t == qi) {
                qv_out[b * HDIM + j] = hn;
                q_ws[b * HDIM + j] = hn;
            }
            if (MODE == 2 && t == T - 1) {
                h_out[b * HDIM + j] = hn;
                if (ep_out) ep_out[b * HDIM + j] = hn;
            }
        }
        __syncthreads();
    }
}

// ---------------------------------------------------------------------------
// K3: attention gates.  WG per batch, 128 threads = (16 t) x (8 segments).
// ---------------------------------------------------------------------------
__global__ __launch_bounds__(128) void k_gates(
    const float* __restrict__ sents, const float* __restrict__ q_ws,
    const float* __restrict__ mem, const float* __restrict__ gate_w,
    const float* __restrict__ gate_b,
    float* __restrict__ gates_ws, float* __restrict__ gout)
{
    int b = blockIdx.x, tid = threadIdx.x;
    int t = tid >> 3, s = tid & 7;
    float p = 0.f;
    const float* sv = sents + ((size_t)b * NSENT + t) * HDIM;
    for (int jj = 0; jj < 16; jj++) {
        int j = s * 16 + jj;
        float S = sv[j], Q = q_ws[b * HDIM + j], M = mem[b * HDIM + j];
        float dq = S - Q, dm = S - M;
        p += (S * Q) * gate_w[j] + (S * M) * gate_w[HDIM + j] +
             (dq * dq) * gate_w[2 * HDIM + j] + (dm * dm) * gate_w[3 * HDIM + j];
    }
    __shared__ float red[16][8];
    red[t][s] = p;
    __syncthreads();
    if (s == 0) {
        float sum = 0.f;
        for (int k = 0; k < 8; k++) sum += red[t][k];
        float gt = sigmf(sum + gate_b[0]);
        gates_ws[b * NSENT + t] = gt;
        if (gout) gout[b * NSENT + t] = gt;
    }
}

// ---------------------------------------------------------------------------
extern "C" void kernel_launch(void* const* d_in, const int* in_sizes, int n_in,
                              void* d_out, int out_size, void* d_ws, size_t ws_size,
                              hipStream_t stream)
{
    const int*   x_sto    = (const int*)d_in[0];
    const int*   x_mask   = (const int*)d_in[1];
    const int*   x_q      = (const int*)d_in[2];
    const float* emb      = (const float*)d_in[4];
    const float* enc_w_ih = (const float*)d_in[5];
    const float* enc_w_hh = (const float*)d_in[6];
    const float* enc_b_ih = (const float*)d_in[7];
    const float* enc_b_hh = (const float*)d_in[8];
    const float* gate_w   = (const float*)d_in[9];
    const float* gate_b   = (const float*)d_in[10];
    const float* ep_w_ih  = (const float*)d_in[11];
    const float* ep_w_hh  = (const float*)d_in[12];
    const float* ep_b_ih  = (const float*)d_in[13];
    const float* ep_b_hh  = (const float*)d_in[14];

    float* out_q  = (float*)d_out;                       // (64,128)
    float* out_ep = (float*)d_out + BATCH * HDIM;        // (1,64,128)
    float* out_g  = (float*)d_out + 2 * BATCH * HDIM;    // (64,16)

    char* ws = (char*)d_ws;
    size_t off = 0;
    auto alloc = [&](size_t bytes) {
        void* p = ws + off;
        off += (bytes + 255) & ~(size_t)255;
        return p;
    };
    __hip_bfloat16* gi_sto = (__hip_bfloat16*)alloc((size_t)BATCH * LSTO * G3 * 2);
    __hip_bfloat16* gi_q   = (__hip_bfloat16*)alloc((size_t)BATCH * QLEN * G3 * 2);
    __hip_bfloat16* gi_ep  = (__hip_bfloat16*)alloc((size_t)BATCH * NSENT * G3 * 2);
    float* sents    = (float*)alloc((size_t)BATCH * NSENT * HDIM * 4);
    float* q_ws     = (float*)alloc((size_t)BATCH * HDIM * 4);
    float* mem      = (float*)alloc((size_t)BATCH * HDIM * 4);
    float* gates_ws = (float*)alloc((size_t)BATCH * NSENT * 4);
    (void)ws_size; (void)in_sizes; (void)n_in; (void)out_size;

    // Phase A: input-projection GEMMs (gather + matmul), bf16 output
    k_gi_gather<<<(BATCH * LSTO) / 32, 192, 0, stream>>>(
        x_sto, BATCH * LSTO, emb, enc_w_ih, enc_b_ih, gi_sto);
    k_gi_gather<<<(BATCH * QLEN) / 32, 192, 0, stream>>>(
        x_q, BATCH * QLEN, emb, enc_w_ih, enc_b_ih, gi_q);

    // Phase B: story scan (writes sents), question scan (writes q_vecs)
    k_scan<0><<<BATCH, 384, 0, stream>>>(
        gi_sto, LSTO, enc_w_hh, enc_b_hh,
        x_mask, sents, nullptr, nullptr, nullptr, nullptr, nullptr, nullptr);
    k_scan<1><<<BATCH, 384, 0, stream>>>(
        gi_q, QLEN, enc_w_hh, enc_b_hh,
        nullptr, nullptr, x_q, out_q, q_ws, nullptr, nullptr, nullptr);

    // Phase C: episodic memory, 3 iterations
    k_gi_dense<<<(BATCH * NSENT) / 32, 192, 0, stream>>>(
        sents, BATCH * NSENT, ep_w_ih, ep_b_ih, gi_ep);

    for (int it = 0; it < 3; ++it) {
        const float* msrc = (it == 0) ? q_ws : mem;
        k_gates<<<BATCH, 128, 0, stream>>>(
            sents, q_ws, msrc, gate_w, gate_b, gates_ws,
            (it == 2) ? out_g : nullptr);
        k_scan<2><<<BATCH, 384, 0, stream>>>(
            gi_ep, NSENT, ep_w_hh, ep_b_hh,
            nullptr, nullptr, nullptr, nullptr, nullptr,
            gates_ws, mem, (it == 2) ? out_ep : nullptr);
    }
}

// Round 8
// 1505.941 us; speedup vs baseline: 1.2427x; 1.1500x over previous
//
#include <hip/hip_runtime.h>
#include <hip/hip_bf16.h>

#define HDIM 128
#define G3 384          // 3*H
#define EDIM 300
#define BATCH 64
#define LSTO 1024
#define QLEN 32
#define NSENT 16

typedef float4 f4;
typedef _Float16 h2 __attribute__((ext_vector_type(2)));
typedef _Float16 h8 __attribute__((ext_vector_type(8)));

__device__ __forceinline__ float sigmf(float x) { return 1.0f / (1.0f + __expf(-x)); }
__device__ __forceinline__ float tanhfast(float x) {
    float e = __expf(-2.0f * x);
    return (1.0f - e) / (1.0f + e);
}

#if __has_builtin(__builtin_amdgcn_fdot2)
__device__ __forceinline__ float dot2f(h2 a, h2 b, float c) {
    return __builtin_amdgcn_fdot2(a, b, c, false);
}
#else
__device__ __forceinline__ float dot2f(h2 a, h2 b, float c) {
    return c + (float)a[0] * (float)b[0] + (float)a[1] * (float)b[1];
}
#endif

__device__ __forceinline__ float bf_lo(unsigned u) { return __uint_as_float(u << 16); }
__device__ __forceinline__ float bf_hi(unsigned u) { return __uint_as_float(u & 0xffff0000u); }

// ---------------------------------------------------------------------------
// K1: gi[row][g] = b_ih[g] + emb[tok[row]] . w_ih[g]   (K = 300), bf16 out
// ---------------------------------------------------------------------------
__global__ __launch_bounds__(192) void k_gi_gather(
    const int* __restrict__ toks, int nrows,
    const float* __restrict__ emb,
    const float* __restrict__ w_ih, const float* __restrict__ b_ih,
    __hip_bfloat16* __restrict__ gi)
{
    __shared__ alignas(16) float a_lds[32 * EDIM];
    int tid = threadIdx.x;
    int rowbase = blockIdx.x * 32;

    for (int i = tid; i < 32 * 75; i += 192) {   // 75 = 300/4
        int r = i / 75, e4 = i - r * 75;
        int row = rowbase + r;
        int tok = (row < nrows) ? toks[row] : 0;
        f4 v = *reinterpret_cast<const f4*>(emb + (size_t)tok * EDIM + e4 * 4);
        *reinterpret_cast<f4*>(a_lds + r * EDIM + e4 * 4) = v;
    }
    __syncthreads();

    int g0 = tid, g1 = tid + 192;
    float acc0[32], acc1[32];
#pragma unroll
    for (int r = 0; r < 32; r++) { acc0[r] = 0.f; acc1[r] = 0.f; }

    const float* w0p = w_ih + (size_t)g0 * EDIM;
    const float* w1p = w_ih + (size_t)g1 * EDIM;
    for (int e4 = 0; e4 < 75; ++e4) {
        f4 w0 = *reinterpret_cast<const f4*>(w0p + e4 * 4);
        f4 w1 = *reinterpret_cast<const f4*>(w1p + e4 * 4);
#pragma unroll
        for (int r = 0; r < 32; r++) {
            f4 a = *reinterpret_cast<const f4*>(a_lds + r * EDIM + e4 * 4);
            acc0[r] += a.x * w0.x + a.y * w0.y + a.z * w0.z + a.w * w0.w;
            acc1[r] += a.x * w1.x + a.y * w1.y + a.z * w1.z + a.w * w1.w;
        }
    }
    float bb0 = b_ih[g0], bb1 = b_ih[g1];
    for (int r = 0; r < 32; r++) {
        int row = rowbase + r;
        if (row < nrows) {
            gi[(size_t)row * G3 + g0] = __float2bfloat16(acc0[r] + bb0);
            gi[(size_t)row * G3 + g1] = __float2bfloat16(acc1[r] + bb1);
        }
    }
}

// ---------------------------------------------------------------------------
// K1b: dense variant, K = 128 (episodic gi from sents)
// ---------------------------------------------------------------------------
__global__ __launch_bounds__(192) void k_gi_dense(
    const float* __restrict__ x, int nrows,
    const float* __restrict__ w_ih, const float* __restrict__ b_ih,
    __hip_bfloat16* __restrict__ gi)
{
    __shared__ alignas(16) float a_lds[32 * HDIM];
    int tid = threadIdx.x;
    int rowbase = blockIdx.x * 32;

    for (int i = tid; i < 32 * 32; i += 192) {   // 32 = 128/4
        int r = i >> 5, e4 = i & 31;
        int row = rowbase + r;
        f4 v;
        if (row < nrows) v = *reinterpret_cast<const f4*>(x + (size_t)row * HDIM + e4 * 4);
        else { v.x = v.y = v.z = v.w = 0.f; }
        *reinterpret_cast<f4*>(a_lds + r * HDIM + e4 * 4) = v;
    }
    __syncthreads();

    int g0 = tid, g1 = tid + 192;
    float acc0[32], acc1[32];
#pragma unroll
    for (int r = 0; r < 32; r++) { acc0[r] = 0.f; acc1[r] = 0.f; }

    const float* w0p = w_ih + (size_t)g0 * HDIM;
    const float* w1p = w_ih + (size_t)g1 * HDIM;
    for (int e4 = 0; e4 < 32; ++e4) {
        f4 w0 = *reinterpret_cast<const f4*>(w0p + e4 * 4);
        f4 w1 = *reinterpret_cast<const f4*>(w1p + e4 * 4);
#pragma unroll
        for (int r = 0; r < 32; r++) {
            f4 a = *reinterpret_cast<const f4*>(a_lds + r * HDIM + e4 * 4);
            acc0[r] += a.x * w0.x + a.y * w0.y + a.z * w0.z + a.w * w0.w;
            acc1[r] += a.x * w1.x + a.y * w1.y + a.z * w1.z + a.w * w1.w;
        }
    }
    float bb0 = b_ih[g0], bb1 = b_ih[g1];
    for (int r = 0; r < 32; r++) {
        int row = rowbase + r;
        if (row < nrows) {
            gi[(size_t)row * G3 + g0] = __float2bfloat16(acc0[r] + bb0);
            gi[(size_t)row * G3 + g1] = __float2bfloat16(acc1[r] + bb1);
        }
    }
}

// ---------------------------------------------------------------------------
// K2: sequential GRU scan, one workgroup per batch element.
// 384 threads (6 waves); thread g holds w_hh row g as 64 named half2 regs
// (64 VGPRs) and accumulates with v_dot2_f32_f16. h state is packed f16 in
// LDS, read as uniform-broadcast b128. Phase 2 runs on 64 threads x 2 elems
// so h can be written back packed.
// ---------------------------------------------------------------------------
#define WD(I) h2 w##I; { float2 t_ = wp2[I];                               \
    w##I = h2{(_Float16)t_.x, (_Float16)t_.y};                             \
    asm volatile("" : "+v"(w##I)); }

#define DOTQ(Q, WA, WB, WC, WE) { h8 hh = hp8[Q];                          \
    a0 = dot2f(WA, h2{hh[0], hh[1]}, a0);                                  \
    a1 = dot2f(WB, h2{hh[2], hh[3]}, a1);                                  \
    a2 = dot2f(WC, h2{hh[4], hh[5]}, a2);                                  \
    a3 = dot2f(WE, h2{hh[6], hh[7]}, a3); }

template <int MODE>
__global__ __launch_bounds__(384, 1) void k_scan(
    const __hip_bfloat16* __restrict__ gi,   // [BATCH*T][384]
    int T,
    const float* __restrict__ w_hh, const float* __restrict__ b_hh,
    const int* __restrict__ mask,            // MODE 0
    float* __restrict__ sents,               // MODE 0
    const int* __restrict__ qtoks,           // MODE 1
    float* __restrict__ qv_out,              // MODE 1 (d_out)
    float* __restrict__ q_ws,                // MODE 1
    const float* __restrict__ gates,         // MODE 2
    float* __restrict__ h_out,               // MODE 2 (mem ws)
    float* __restrict__ ep_out)              // MODE 2 (d_out, nullable)
{
    __shared__ alignas(16) h2 h_lds2[HDIM / 2];   // packed f16 h state
    __shared__ alignas(8) float gh_lds[G3];

    int tid = threadIdx.x;          // 0..383, = output gate index g
    int b = blockIdx.x;

    const float2* wp2 = reinterpret_cast<const float2*>(w_hh + (size_t)tid * HDIM);
    WD(0)  WD(1)  WD(2)  WD(3)  WD(4)  WD(5)  WD(6)  WD(7)
    WD(8)  WD(9)  WD(10) WD(11) WD(12) WD(13) WD(14) WD(15)
    WD(16) WD(17) WD(18) WD(19) WD(20) WD(21) WD(22) WD(23)
    WD(24) WD(25) WD(26) WD(27) WD(28) WD(29) WD(30) WD(31)
    WD(32) WD(33) WD(34) WD(35) WD(36) WD(37) WD(38) WD(39)
    WD(40) WD(41) WD(42) WD(43) WD(44) WD(45) WD(46) WD(47)
    WD(48) WD(49) WD(50) WD(51) WD(52) WD(53) WD(54) WD(55)
    WD(56) WD(57) WD(58) WD(59) WD(60) WD(61) WD(62) WD(63)
    float bb = b_hh[tid];

    if (tid < HDIM / 2) h_lds2[tid] = h2{(_Float16)0.f, (_Float16)0.f};

    int qi = QLEN - 1;
    if (MODE == 1) {
        for (int t2 = QLEN - 2; t2 >= 0; --t2)
            if (qtoks[b * QLEN + t2 + 1] == 0) qi = t2;
    }
    int scnt = 0;
    __syncthreads();

    const __hip_bfloat16* gib = gi + (size_t)b * T * G3;
    const h8* hp8 = reinterpret_cast<const h8*>(h_lds2);

    for (int t = 0; t < T; ++t) {
        // ---- phase 0: prefetch this step's gi (+mask/gate), tid<64 ----
        unsigned rr = 0, zz = 0, nn = 0;
        int m = 0;
        float wgate = 0.f;
        if (tid < HDIM / 2) {
            const unsigned short* gr =
                reinterpret_cast<const unsigned short*>(gib + (size_t)t * G3);
            rr = *reinterpret_cast<const unsigned*>(gr + 2 * tid);
            zz = *reinterpret_cast<const unsigned*>(gr + HDIM + 2 * tid);
            nn = *reinterpret_cast<const unsigned*>(gr + 2 * HDIM + 2 * tid);
            if (MODE == 0) m = mask[b * LSTO + t];
            if (MODE == 2) wgate = gates[b * NSENT + t];
        }

        // ---- phase 1: gh[g] = bb + h . w  (64 dot2, 4 accumulators) ----
        float a0 = bb, a1 = 0.f, a2 = 0.f, a3 = 0.f;
        DOTQ(0,  w0,  w1,  w2,  w3)   DOTQ(1,  w4,  w5,  w6,  w7)
        DOTQ(2,  w8,  w9,  w10, w11)  DOTQ(3,  w12, w13, w14, w15)
        DOTQ(4,  w16, w17, w18, w19)  DOTQ(5,  w20, w21, w22, w23)
        DOTQ(6,  w24, w25, w26, w27)  DOTQ(7,  w28, w29, w30, w31)
        DOTQ(8,  w32, w33, w34, w35)  DOTQ(9,  w36, w37, w38, w39)
        DOTQ(10, w40, w41, w42, w43)  DOTQ(11, w44, w45, w46, w47)
        DOTQ(12, w48, w49, w50, w51)  DOTQ(13, w52, w53, w54, w55)
        DOTQ(14, w56, w57, w58, w59)  DOTQ(15, w60, w61, w62, w63)
        gh_lds[tid] = (a0 + a1) + (a2 + a3);
        __syncthreads();

        // ---- phase 2: elementwise GRU cell, 64 threads x 2 elements ----
        if (tid < HDIM / 2) {
            int j0 = 2 * tid;
            float2 ghr = *reinterpret_cast<const float2*>(gh_lds + j0);
            float2 ghz = *reinterpret_cast<const float2*>(gh_lds + HDIM + j0);
            float2 ghn = *reinterpret_cast<const float2*>(gh_lds + 2 * HDIM + j0);
            h2 hv = h_lds2[tid];
            float hp0 = (float)hv[0], hp1 = (float)hv[1];

            float r0 = sigmf(bf_lo(rr) + ghr.x);
            float r1 = sigmf(bf_hi(rr) + ghr.y);
            float z0 = sigmf(bf_lo(zz) + ghz.x);
            float z1 = sigmf(bf_hi(zz) + ghz.y);
            float n0 = tanhfast(bf_lo(nn) + r0 * ghn.x);
            float n1 = tanhfast(bf_hi(nn) + r1 * ghn.y);
            float hn0 = (1.f - z0) * n0 + z0 * hp0;
            float hn1 = (1.f - z1) * n1 + z1 * hp1;
            if (MODE == 2) {
                hn0 = wgate * hn0 + (1.f - wgate) * hp0;
                hn1 = wgate * hn1 + (1.f - wgate) * hp1;
            }
            h_lds2[tid] = h2{(_Float16)hn0, (_Float16)hn1};

            if (MODE == 0) {
                if (m) {
                    if (scnt < NSENT) {
                        float* sp = sents + ((size_t)b * NSENT + scnt) * HDIM + j0;
                        sp[0] = hn0; sp[1] = hn1;
                    }
                    scnt++;
                }
            }
            if (MODE == 1 && t == qi) {
                qv_out[b * HDIM + j0] = hn0; qv_out[b * HDIM + j0 + 1] = hn1;
                q_ws[b * HDIM + j0] = hn0;   q_ws[b * HDIM + j0 + 1] = hn1;
            }
            if (MODE == 2 && t == T - 1) {
                h_out[b * HDIM + j0] = hn0;  h_out[b * HDIM + j0 + 1] = hn1;
                if (ep_out) {
                    ep_out[b * HDIM + j0] = hn0; ep_out[b * HDIM + j0 + 1] = hn1;
                }
            }
        }
        __syncthreads();
    }
}

// ---------------------------------------------------------------------------
// K3: attention gates.  WG per batch, 128 threads = (16 t) x (8 segments).
// ---------------------------------------------------------------------------
__global__ __launch_bounds__(128) void k_gates(
    const float* __restrict__ sents, const float* __restrict__ q_ws,
    const float* __restrict__ mem, const float* __restrict__ gate_w,
    const float* __restrict__ gate_b,
    float* __restrict__ gates_ws, float* __restrict__ gout)
{
    int b = blockIdx.x, tid = threadIdx.x;
    int t = tid >> 3, s = tid & 7;
    float p = 0.f;
    const float* sv = sents + ((size_t)b * NSENT + t) * HDIM;
    for (int jj = 0; jj < 16; jj++) {
        int j = s * 16 + jj;
        float S = sv[j], Q = q_ws[b * HDIM + j], M = mem[b * HDIM + j];
        float dq = S - Q, dm = S - M;
        p += (S * Q) * gate_w[j] + (S * M) * gate_w[HDIM + j] +
             (dq * dq) * gate_w[2 * HDIM + j] + (dm * dm) * gate_w[3 * HDIM + j];
    }
    __shared__ float red[16][8];
    red[t][s] = p;
    __syncthreads();
    if (s == 0) {
        float sum = 0.f;
        for (int k = 0; k < 8; k++) sum += red[t][k];
        float gt = sigmf(sum + gate_b[0]);
        gates_ws[b * NSENT + t] = gt;
        if (gout) gout[b * NSENT + t] = gt;
    }
}

// ---------------------------------------------------------------------------
extern "C" void kernel_launch(void* const* d_in, const int* in_sizes, int n_in,
                              void* d_out, int out_size, void* d_ws, size_t ws_size,
                              hipStream_t stream)
{
    const int*   x_sto    = (const int*)d_in[0];
    const int*   x_mask   = (const int*)d_in[1];
    const int*   x_q      = (const int*)d_in[2];
    const float* emb      = (const float*)d_in[4];
    const float* enc_w_ih = (const float*)d_in[5];
    const float* enc_w_hh = (const float*)d_in[6];
    const float* enc_b_ih = (const float*)d_in[7];
    const float* enc_b_hh = (const float*)d_in[8];
    const float* gate_w   = (const float*)d_in[9];
    const float* gate_b   = (const float*)d_in[10];
    const float* ep_w_ih  = (const float*)d_in[11];
    const float* ep_w_hh  = (const float*)d_in[12];
    const float* ep_b_ih  = (const float*)d_in[13];
    const float* ep_b_hh  = (const float*)d_in[14];

    float* out_q  = (float*)d_out;                       // (64,128)
    float* out_ep = (float*)d_out + BATCH * HDIM;        // (1,64,128)
    float* out_g  = (float*)d_out + 2 * BATCH * HDIM;    // (64,16)

    char* ws = (char*)d_ws;
    size_t off = 0;
    auto alloc = [&](size_t bytes) {
        void* p = ws + off;
        off += (bytes + 255) & ~(size_t)255;
        return p;
    };
    __hip_bfloat16* gi_sto = (__hip_bfloat16*)alloc((size_t)BATCH * LSTO * G3 * 2);
    __hip_bfloat16* gi_q   = (__hip_bfloat16*)alloc((size_t)BATCH * QLEN * G3 * 2);
    __hip_bfloat16* gi_ep  = (__hip_bfloat16*)alloc((size_t)BATCH * NSENT * G3 * 2);
    float* sents    = (float*)alloc((size_t)BATCH * NSENT * HDIM * 4);
    float* q_ws     = (float*)alloc((size_t)BATCH * HDIM * 4);
    float* mem      = (float*)alloc((size_t)BATCH * HDIM * 4);
    float* gates_ws = (float*)alloc((size_t)BATCH * NSENT * 4);
    (void)ws_size; (void)in_sizes; (void)n_in; (void)out_size;

    // Phase A: input-projection GEMMs (gather + matmul), bf16 output
    k_gi_gather<<<(BATCH * LSTO) / 32, 192, 0, stream>>>(
        x_sto, BATCH * LSTO, emb, enc_w_ih, enc_b_ih, gi_sto);
    k_gi_gather<<<(BATCH * QLEN) / 32, 192, 0, stream>>>(
        x_q, BATCH * QLEN, emb, enc_w_ih, enc_b_ih, gi_q);

    // Phase B: story scan (writes sents), question scan (writes q_vecs)
    k_scan<0><<<BATCH, 384, 0, stream>>>(
        gi_sto, LSTO, enc_w_hh, enc_b_hh,
        x_mask, sents, nullptr, nullptr, nullptr, nullptr, nullptr, nullptr);
    k_scan<1><<<BATCH, 384, 0, stream>>>(
        gi_q, QLEN, enc_w_hh, enc_b_hh,
        nullptr, nullptr, x_q, out_q, q_ws, nullptr, nullptr, nullptr);

    // Phase C: episodic memory, 3 iterations
    k_gi_dense<<<(BATCH * NSENT) / 32, 192, 0, stream>>>(
        sents, BATCH * NSENT, ep_w_ih, ep_b_ih, gi_ep);

    for (int it = 0; it < 3; ++it) {
        const float* msrc = (it == 0) ? q_ws : mem;
        k_gates<<<BATCH, 128, 0, stream>>>(
            sents, q_ws, msrc, gate_w, gate_b, gates_ws,
            (it == 2) ? out_g : nullptr);
        k_scan<2><<<BATCH, 384, 0, stream>>>(
            gi_ep, NSENT, ep_w_hh, ep_b_hh,
            nullptr, nullptr, nullptr, nullptr, nullptr,
            gates_ws, mem, (it == 2) ? out_ep : nullptr);
    }
}